// Round 4
// baseline (2024.037 us; speedup 1.0000x reference)
//
#include <hip/hip_runtime.h>

// ---------------------------------------------------------------------------
// Mamba block forward on MI355X (gfx950).
// B=2, L=2048, D_MODEL=1024, D_INNER=2048, D_STATE=128, D_CONV=4, DT_RANK=64
// ---------------------------------------------------------------------------

typedef short bf16x8 __attribute__((ext_vector_type(8)));
typedef float f32x4 __attribute__((ext_vector_type(4)));

typedef __attribute__((address_space(1))) const unsigned int GASU;
typedef __attribute__((address_space(3))) unsigned int LASU;

__device__ __forceinline__ void gload16(const void* g, void* l) {
  __builtin_amdgcn_global_load_lds((GASU*)g, (LASU*)l, 16, 0, 0);
}

// round-to-nearest-even f32 -> bf16 bits
__device__ __forceinline__ unsigned short f2b(float f) {
  unsigned int u = __float_as_uint(f);
  unsigned int r = u + 0x7FFFu + ((u >> 16) & 1u);
  return (unsigned short)(r >> 16);
}

// ---------------------------------------------------------------------------
// elementwise cast fp32 -> bf16
__global__ __launch_bounds__(256) void cast_b16(const float* __restrict__ in,
                                                unsigned short* __restrict__ out,
                                                int n) {
  int i = blockIdx.x * 256 + threadIdx.x;
  if (i < n) out[i] = f2b(in[i]);
}

// ---------------------------------------------------------------------------
// transpose + cast: out[c][r] = bf16(in[r][c]).  R, C multiples of 32.
__global__ __launch_bounds__(256) void transpose_cast(const float* __restrict__ in,
                                                      unsigned short* __restrict__ out,
                                                      int R, int C) {
  __shared__ float tile[32][33];
  int bx = blockIdx.x * 32;  // col base (in)
  int by = blockIdx.y * 32;  // row base (in)
  int lx = threadIdx.x & 31, ly = threadIdx.x >> 5;  // ly: 0..7
#pragma unroll
  for (int i = 0; i < 32; i += 8)
    tile[ly + i][lx] = in[(size_t)(by + ly + i) * C + bx + lx];
  __syncthreads();
#pragma unroll
  for (int i = 0; i < 32; i += 8)
    out[(size_t)(bx + ly + i) * R + by + lx] = f2b(tile[lx][ly + i]);
}

// ---------------------------------------------------------------------------
// bf16 MFMA GEMM: C[M][N] (fp32) = A[M][K] (bf16) * Bt[N][K]^T (bf16)
// 128x128 tile, BK=32, 256 threads (4 waves, each a 64x64 quadrant of 4x4
// 16x16x32 MFMAs). global_load_lds width-16 staging (m97 structure).
// EPI==1: C = softplus(C + bias[col])
// M multiple of 128, K multiple of 32. N arbitrary (edge-masked store).
template <int EPI>
__global__ __launch_bounds__(256) void gemm_bt(const unsigned short* __restrict__ A,
                                               const unsigned short* __restrict__ Bt,
                                               float* __restrict__ C, int M, int N,
                                               int K, const float* __restrict__ bias) {
  __shared__ __align__(16) unsigned short As[128 * 32];
  __shared__ __align__(16) unsigned short Bs[128 * 32];
  int tid = threadIdx.x;
  int wave = tid >> 6, lane = tid & 63;
  int m0 = blockIdx.y * 128, n0 = blockIdx.x * 128;
  int wm = (wave >> 1) * 64, wn = (wave & 1) * 64;

  f32x4 acc[4][4];
#pragma unroll
  for (int i = 0; i < 4; i++)
#pragma unroll
    for (int j = 0; j < 4; j++) acc[i][j] = (f32x4){0.f, 0.f, 0.f, 0.f};

  // staging geometry: each issue covers 64 rows x 32 cols (bf16); a wave
  // covers 16 rows (1 KiB). lane -> row = base + lane/4, col8 = (lane%4)*8.
  int srow = wave * 16 + (lane >> 2);
  int scol = (lane & 3) * 8;
  unsigned short* lA0 = &As[(wave * 16) * 32];
  unsigned short* lA1 = &As[(64 + wave * 16) * 32];
  unsigned short* lB0 = &Bs[(wave * 16) * 32];
  unsigned short* lB1 = &Bs[(64 + wave * 16) * 32];

  for (int k0 = 0; k0 < K; k0 += 32) {
    const unsigned short* gA0 = A + (size_t)(m0 + srow) * K + k0 + scol;
    const unsigned short* gA1 = A + (size_t)(m0 + 64 + srow) * K + k0 + scol;
    int rb0 = n0 + srow;      if (rb0 > N - 1) rb0 = N - 1;
    int rb1 = n0 + 64 + srow; if (rb1 > N - 1) rb1 = N - 1;
    const unsigned short* gB0 = Bt + (size_t)rb0 * K + k0 + scol;
    const unsigned short* gB1 = Bt + (size_t)rb1 * K + k0 + scol;
    gload16(gA0, lA0);
    gload16(gA1, lA1);
    gload16(gB0, lB0);
    gload16(gB1, lB1);
    __syncthreads();  // drains vmcnt: staged tile visible to all waves

    int lm = lane & 15, kk = (lane >> 4) * 8;
    bf16x8 af[4], bfr[4];
#pragma unroll
    for (int i = 0; i < 4; i++)
      af[i] = *(const bf16x8*)&As[(wm + i * 16 + lm) * 32 + kk];
#pragma unroll
    for (int j = 0; j < 4; j++)
      bfr[j] = *(const bf16x8*)&Bs[(wn + j * 16 + lm) * 32 + kk];
#pragma unroll
    for (int i = 0; i < 4; i++)
#pragma unroll
      for (int j = 0; j < 4; j++)
        acc[i][j] = __builtin_amdgcn_mfma_f32_16x16x32_bf16(af[i], bfr[j],
                                                            acc[i][j], 0, 0, 0);
    __syncthreads();  // all reads done before next-tile overwrite
  }

  // C/D layout (verified): col = lane&15, row = (lane>>4)*4 + reg
  int lm = lane & 15;
  int r0 = m0 + wm + (lane >> 4) * 4;
#pragma unroll
  for (int i = 0; i < 4; i++) {
#pragma unroll
    for (int j = 0; j < 4; j++) {
      int col = n0 + wn + j * 16 + lm;
      if (col < N) {
#pragma unroll
        for (int q = 0; q < 4; q++) {
          float v = acc[i][j][q];
          if (EPI == 1) {
            v += bias[col];
            v = (v > 20.f) ? v : __logf(1.f + __expf(v));
          }
          C[(size_t)(r0 + i * 16 + q) * N + col] = v;
        }
      }
    }
  }
}

// ---------------------------------------------------------------------------
// causal depthwise conv (k=4) + bias + SiLU.  x = xz[:, 0:2048].
// writes x_silu fp32 (scan input u) and bf16 (x_proj GEMM input).
__global__ __launch_bounds__(256) void conv_silu_kernel(
    const float* __restrict__ xz, const float* __restrict__ cw,
    const float* __restrict__ cb, float* __restrict__ xs,
    unsigned short* __restrict__ xsb) {
  int idx = blockIdx.x * 256 + threadIdx.x;  // over 4096*2048
  int d = idx & 2047;
  int row = idx >> 11;  // b*2048 + t
  int t = row & 2047;
  float w0 = cw[d * 4 + 0], w1 = cw[d * 4 + 1], w2 = cw[d * 4 + 2],
        w3 = cw[d * 4 + 3];
  float acc = cb[d];
  if (t >= 3) acc = fmaf(w0, xz[(size_t)(row - 3) * 4096 + d], acc);
  if (t >= 2) acc = fmaf(w1, xz[(size_t)(row - 2) * 4096 + d], acc);
  if (t >= 1) acc = fmaf(w2, xz[(size_t)(row - 1) * 4096 + d], acc);
  acc = fmaf(w3, xz[(size_t)row * 4096 + d], acc);
  float s = acc / (1.f + __expf(-acc));
  xs[(size_t)row * 2048 + d] = s;
  xsb[(size_t)row * 2048 + d] = f2b(s);
}

// ---------------------------------------------------------------------------
// slice x_dbl[:, 0:64] -> bf16 (dt GEMM A operand)
__global__ __launch_bounds__(256) void slice_cast(const float* __restrict__ xdbl,
                                                  unsigned short* __restrict__ dtin) {
  int idx = blockIdx.x * 256 + threadIdx.x;  // 4096*64
  int r = idx >> 6, i = idx & 63;
  dtin[idx] = f2b(xdbl[(size_t)r * 320 + i]);
}

// ---------------------------------------------------------------------------
// selective scan, fused with skip (u*D) and output gate silu(z); writes y bf16.
// Layout v2: wave = 1 channel (b,d); 64 lanes x 2 states. block = 4 channels.
// grid = 1024 blocks -> 4 blocks/CU, 16 waves/CU (2x the v1 latency hiding).
// ALL five streams (B, C, dt, u, z) prefetched one t ahead; pointer-increment
// addressing (no per-iter 64-bit muls).
// NOTE: the t = L-1 prefetch reads one row past each stream; all five streams
// are followed by other ws regions, so the (discarded) reads stay in-bounds
// of d_ws.
__global__ __launch_bounds__(256) void scan_kernel(
    const float* __restrict__ dtp, const float* __restrict__ xs,
    const float* __restrict__ xdbl, const float* __restrict__ xz,
    const float* __restrict__ A_log, const float* __restrict__ Dp,
    unsigned short* __restrict__ yb) {
  const int L = 2048, DI = 2048, XD = 320;
  int blk = blockIdx.x;
  int b = blk >> 9;                      // batch
  int wave = threadIdx.x >> 6, g = threadIdx.x & 63;
  int d = (blk & 511) * 4 + wave;        // channel

  float a0 = -__expf(A_log[d * 128 + 2 * g + 0]);
  float a1 = -__expf(A_log[d * 128 + 2 * g + 1]);
  float Dd = Dp[d];
  float h0 = 0.f, h1 = 0.f;

  size_t row0 = (size_t)b * L;
  const float* pB  = xdbl + row0 * XD + 64 + 2 * g;
  const float* pC  = xdbl + row0 * XD + 192 + 2 * g;
  const float* pDT = dtp + row0 * DI + d;
  const float* pU  = xs + row0 * DI + d;
  const float* pZ  = xz + row0 * 4096 + 2048 + d;
  unsigned short* pY = yb + row0 * DI + d;

  // prefetch t=0
  float2 Bv = *(const float2*)pB;
  float2 Cv = *(const float2*)pC;
  float dtv = *pDT, uv = *pU, zv = *pZ;

  for (int t = 0; t < L; ++t) {
    // issue t+1 prefetch first (covered by this iteration's compute)
    pB += XD; pC += XD; pDT += DI; pU += DI; pZ += 4096;
    float2 Bn = *(const float2*)pB;
    float2 Cn = *(const float2*)pC;
    float dtn = *pDT;
    float un = *pU;
    float zn = *pZ;

    float du = dtv * uv;
    h0 = fmaf(__expf(dtv * a0), h0, du * Bv.x);
    h1 = fmaf(__expf(dtv * a1), h1, du * Bv.y);
    float p = fmaf(h0, Cv.x, h1 * Cv.y);
    p += __shfl_xor(p, 32);
    p += __shfl_xor(p, 16);
    p += __shfl_xor(p, 8);
    p += __shfl_xor(p, 4);
    p += __shfl_xor(p, 2);
    p += __shfl_xor(p, 1);
    if (g == 0) {
      float yv = fmaf(uv, Dd, p);
      yv *= zv / (1.f + __expf(-zv));  // * silu(z)
      *pY = f2b(yv);
    }
    pY += DI;
    Bv = Bn; Cv = Cn; dtv = dtn; uv = un; zv = zn;
  }
}

// ---------------------------------------------------------------------------
extern "C" void kernel_launch(void* const* d_in, const int* in_sizes, int n_in,
                              void* d_out, int out_size, void* d_ws, size_t ws_size,
                              hipStream_t stream) {
  const float* hidden  = (const float*)d_in[0];  // (2,2048,1024)
  const float* W_in    = (const float*)d_in[1];  // (1024,4096)
  const float* conv_w  = (const float*)d_in[2];  // (2048,1,4)
  const float* conv_b  = (const float*)d_in[3];  // (2048,)
  const float* W_xproj = (const float*)d_in[4];  // (2048,320)
  const float* W_dt    = (const float*)d_in[5];  // (64,2048)
  const float* b_dt    = (const float*)d_in[6];  // (2048,)
  const float* A_log   = (const float*)d_in[7];  // (2048,128)
  const float* Dvec    = (const float*)d_in[8];  // (2048,)
  const float* W_out   = (const float*)d_in[9];  // (2048,1024)
  float* out = (float*)d_out;                    // (2,2048,1024) fp32

  char* ws = (char*)d_ws;
  unsigned short* hb16  = (unsigned short*)(ws + 0);          //  8 MB (4096x1024 bf16)
  unsigned short* Wint  = (unsigned short*)(ws + 8388608);    //  8 MB [4096][1024]
  float*          xz    = (float*)(ws + 16777216);            // 64 MB [4096][4096]
  float*          xs    = (float*)(ws + 83886080);            // 32 MB [4096][2048]
  unsigned short* xsb   = (unsigned short*)(ws + 117440512);  // 16 MB
  float*          xdbl  = (float*)(ws + 134217728);           //  5 MB [4096][320]
  unsigned short* dtin  = (unsigned short*)(ws + 139460608);  // .5 MB [4096][64]
  unsigned short* Wxpt  = (unsigned short*)(ws + 139984896);  // 1.3MB [320][2048]
  unsigned short* Wdtt  = (unsigned short*)(ws + 141295616);  // .25MB [2048][64]
  float*          dtf   = (float*)(ws + 141557760);           // 32 MB [4096][2048]
  unsigned short* yb    = (unsigned short*)(ws + 175112192);  // 16 MB [4096][2048]
  unsigned short* Woutt = (unsigned short*)(ws + 191889408);  //  4 MB [1024][2048]

  // 1) operand conversion
  cast_b16<<<16384, 256, 0, stream>>>(hidden, hb16, 4194304);
  transpose_cast<<<dim3(128, 32), 256, 0, stream>>>(W_in, Wint, 1024, 4096);
  // 2) in_proj: xz = hidden @ W_in   (M=4096, N=4096, K=1024)
  gemm_bt<0><<<dim3(32, 32), 256, 0, stream>>>(hb16, Wint, xz, 4096, 4096, 1024, nullptr);
  // 3) causal depthwise conv + SiLU
  conv_silu_kernel<<<32768, 256, 0, stream>>>(xz, conv_w, conv_b, xs, xsb);
  // 4) x_proj: x_dbl = x @ W_xproj  (M=4096, N=320, K=2048)
  transpose_cast<<<dim3(10, 64), 256, 0, stream>>>(W_xproj, Wxpt, 2048, 320);
  gemm_bt<0><<<dim3(3, 32), 256, 0, stream>>>(xsb, Wxpt, xdbl, 4096, 320, 2048, nullptr);
  // 5) dt: softplus(dt_in @ W_dt + b_dt)  (M=4096, N=2048, K=64)
  slice_cast<<<1024, 256, 0, stream>>>(xdbl, dtin);
  transpose_cast<<<dim3(64, 2), 256, 0, stream>>>(W_dt, Wdtt, 64, 2048);
  gemm_bt<1><<<dim3(16, 32), 256, 0, stream>>>(dtin, Wdtt, dtf, 4096, 2048, 64, b_dt);
  // 6) selective scan + skip + gate -> y (bf16)
  scan_kernel<<<1024, 256, 0, stream>>>(dtf, xs, xdbl, xz, A_log, Dvec, yb);
  // 7) out_proj: out = y @ W_out  (M=4096, N=1024, K=2048)
  transpose_cast<<<dim3(32, 64), 256, 0, stream>>>(W_out, Woutt, 2048, 1024);
  gemm_bt<0><<<dim3(8, 32), 256, 0, stream>>>(yb, Woutt, out, 4096, 1024, 2048, nullptr);
}

// Round 8
// 1067.826 us; speedup vs baseline: 1.8955x; 1.8955x over previous
//
#include <hip/hip_runtime.h>

// ---------------------------------------------------------------------------
// Mamba block forward on MI355X (gfx950).
// B=2, L=2048, D_MODEL=1024, D_INNER=2048, D_STATE=128, D_CONV=4, DT_RANK=64
// ---------------------------------------------------------------------------

typedef short bf16x8 __attribute__((ext_vector_type(8)));
typedef float f32x4 __attribute__((ext_vector_type(4)));

typedef __attribute__((address_space(1))) const unsigned int GASU;
typedef __attribute__((address_space(3))) unsigned int LASU;

__device__ __forceinline__ void gload16(const void* g, void* l) {
  __builtin_amdgcn_global_load_lds((GASU*)g, (LASU*)l, 16, 0, 0);
}
__device__ __forceinline__ void gload4(const void* g, void* l) {
  __builtin_amdgcn_global_load_lds((GASU*)g, (LASU*)l, 4, 0, 0);
}

// round-to-nearest-even f32 -> bf16 bits
__device__ __forceinline__ unsigned short f2b(float f) {
  unsigned int u = __float_as_uint(f);
  unsigned int r = u + 0x7FFFu + ((u >> 16) & 1u);
  return (unsigned short)(r >> 16);
}

// ---------------------------------------------------------------------------
// elementwise cast fp32 -> bf16
__global__ __launch_bounds__(256) void cast_b16(const float* __restrict__ in,
                                                unsigned short* __restrict__ out,
                                                int n) {
  int i = blockIdx.x * 256 + threadIdx.x;
  if (i < n) out[i] = f2b(in[i]);
}

// ---------------------------------------------------------------------------
// transpose + cast: out[c][r] = bf16(in[r][c]).  R, C multiples of 32.
__global__ __launch_bounds__(256) void transpose_cast(const float* __restrict__ in,
                                                      unsigned short* __restrict__ out,
                                                      int R, int C) {
  __shared__ float tile[32][33];
  int bx = blockIdx.x * 32;  // col base (in)
  int by = blockIdx.y * 32;  // row base (in)
  int lx = threadIdx.x & 31, ly = threadIdx.x >> 5;  // ly: 0..7
#pragma unroll
  for (int i = 0; i < 32; i += 8)
    tile[ly + i][lx] = in[(size_t)(by + ly + i) * C + bx + lx];
  __syncthreads();
#pragma unroll
  for (int i = 0; i < 32; i += 8)
    out[(size_t)(bx + ly + i) * R + by + lx] = f2b(tile[lx][ly + i]);
}

// ---------------------------------------------------------------------------
// bf16 MFMA GEMM: C[M][N] (fp32) = A[M][K] (bf16) * Bt[N][K]^T (bf16)
// 128x128 tile, BK=32, 256 threads (4 waves, each a 64x64 quadrant of 4x4
// 16x16x32 MFMAs). global_load_lds width-16 staging (m97 structure).
// EPI==1: C = softplus(C + bias[col])
// M multiple of 128, K multiple of 32. N arbitrary (edge-masked store).
template <int EPI>
__global__ __launch_bounds__(256) void gemm_bt(const unsigned short* __restrict__ A,
                                               const unsigned short* __restrict__ Bt,
                                               float* __restrict__ C, int M, int N,
                                               int K, const float* __restrict__ bias) {
  __shared__ __align__(16) unsigned short As[128 * 32];
  __shared__ __align__(16) unsigned short Bs[128 * 32];
  int tid = threadIdx.x;
  int wave = tid >> 6, lane = tid & 63;
  int m0 = blockIdx.y * 128, n0 = blockIdx.x * 128;
  int wm = (wave >> 1) * 64, wn = (wave & 1) * 64;

  f32x4 acc[4][4];
#pragma unroll
  for (int i = 0; i < 4; i++)
#pragma unroll
    for (int j = 0; j < 4; j++) acc[i][j] = (f32x4){0.f, 0.f, 0.f, 0.f};

  // staging geometry: each issue covers 64 rows x 32 cols (bf16); a wave
  // covers 16 rows (1 KiB). lane -> row = base + lane/4, col8 = (lane%4)*8.
  int srow = wave * 16 + (lane >> 2);
  int scol = (lane & 3) * 8;
  unsigned short* lA0 = &As[(wave * 16) * 32];
  unsigned short* lA1 = &As[(64 + wave * 16) * 32];
  unsigned short* lB0 = &Bs[(wave * 16) * 32];
  unsigned short* lB1 = &Bs[(64 + wave * 16) * 32];

  for (int k0 = 0; k0 < K; k0 += 32) {
    const unsigned short* gA0 = A + (size_t)(m0 + srow) * K + k0 + scol;
    const unsigned short* gA1 = A + (size_t)(m0 + 64 + srow) * K + k0 + scol;
    int rb0 = n0 + srow;      if (rb0 > N - 1) rb0 = N - 1;
    int rb1 = n0 + 64 + srow; if (rb1 > N - 1) rb1 = N - 1;
    const unsigned short* gB0 = Bt + (size_t)rb0 * K + k0 + scol;
    const unsigned short* gB1 = Bt + (size_t)rb1 * K + k0 + scol;
    gload16(gA0, lA0);
    gload16(gA1, lA1);
    gload16(gB0, lB0);
    gload16(gB1, lB1);
    __syncthreads();  // drains vmcnt: staged tile visible to all waves

    int lm = lane & 15, kk = (lane >> 4) * 8;
    bf16x8 af[4], bfr[4];
#pragma unroll
    for (int i = 0; i < 4; i++)
      af[i] = *(const bf16x8*)&As[(wm + i * 16 + lm) * 32 + kk];
#pragma unroll
    for (int j = 0; j < 4; j++)
      bfr[j] = *(const bf16x8*)&Bs[(wn + j * 16 + lm) * 32 + kk];
#pragma unroll
    for (int i = 0; i < 4; i++)
#pragma unroll
      for (int j = 0; j < 4; j++)
        acc[i][j] = __builtin_amdgcn_mfma_f32_16x16x32_bf16(af[i], bfr[j],
                                                            acc[i][j], 0, 0, 0);
    __syncthreads();  // all reads done before next-tile overwrite
  }

  // C/D layout (verified): col = lane&15, row = (lane>>4)*4 + reg
  int lm = lane & 15;
  int r0 = m0 + wm + (lane >> 4) * 4;
#pragma unroll
  for (int i = 0; i < 4; i++) {
#pragma unroll
    for (int j = 0; j < 4; j++) {
      int col = n0 + wn + j * 16 + lm;
      if (col < N) {
#pragma unroll
        for (int q = 0; q < 4; q++) {
          float v = acc[i][j][q];
          if (EPI == 1) {
            v += bias[col];
            v = (v > 20.f) ? v : __logf(1.f + __expf(v));
          }
          C[(size_t)(r0 + i * 16 + q) * N + col] = v;
        }
      }
    }
  }
}

// ---------------------------------------------------------------------------
// causal depthwise conv (k=4) + bias + SiLU.  x = xz[:, 0:2048].
// writes x_silu fp32 (scan input u) and bf16 (x_proj GEMM input).
__global__ __launch_bounds__(256) void conv_silu_kernel(
    const float* __restrict__ xz, const float* __restrict__ cw,
    const float* __restrict__ cb, float* __restrict__ xs,
    unsigned short* __restrict__ xsb) {
  int idx = blockIdx.x * 256 + threadIdx.x;  // over 4096*2048
  int d = idx & 2047;
  int row = idx >> 11;  // b*2048 + t
  int t = row & 2047;
  float w0 = cw[d * 4 + 0], w1 = cw[d * 4 + 1], w2 = cw[d * 4 + 2],
        w3 = cw[d * 4 + 3];
  float acc = cb[d];
  if (t >= 3) acc = fmaf(w0, xz[(size_t)(row - 3) * 4096 + d], acc);
  if (t >= 2) acc = fmaf(w1, xz[(size_t)(row - 2) * 4096 + d], acc);
  if (t >= 1) acc = fmaf(w2, xz[(size_t)(row - 1) * 4096 + d], acc);
  acc = fmaf(w3, xz[(size_t)row * 4096 + d], acc);
  float s = acc / (1.f + __expf(-acc));
  xs[(size_t)row * 2048 + d] = s;
  xsb[(size_t)row * 2048 + d] = f2b(s);
}

// ---------------------------------------------------------------------------
// slice x_dbl[:, 0:64] -> bf16 (dt GEMM A operand)
__global__ __launch_bounds__(256) void slice_cast(const float* __restrict__ xdbl,
                                                  unsigned short* __restrict__ dtin) {
  int idx = blockIdx.x * 256 + threadIdx.x;  // 4096*64
  int r = idx >> 6, i = idx & 63;
  dtin[idx] = f2b(xdbl[(size_t)r * 320 + i]);
}

// ---------------------------------------------------------------------------
// selective scan v3: time-tiled double-buffered LDS staging.
// Block = 256 threads = 8 channels x (32 lanes x 4 states); grid = 512.
// Per TC=32-step chunk, async-stage into LDS via global_load_lds:
//   BC : B|C cols 64..320 of xdbl -> 1 KB/row, 1 width-16 issue per row/wave
//   DT/U/Z : 32 rows x 8 ch, 1 width-4 issue per stream per wave
// Chunk k+1 staged before computing chunk k (one barrier per chunk, m97
// overlap pattern). Inner loop reads LDS only.
__global__ __launch_bounds__(256) void scan_kernel(
    const float* __restrict__ dtp, const float* __restrict__ xs,
    const float* __restrict__ xdbl, const float* __restrict__ xz,
    const float* __restrict__ A_log, const float* __restrict__ Dp,
    unsigned short* __restrict__ yb) {
  const int L = 2048, DI = 2048, XD = 320, TC = 32;
  const int NCHUNK = L / TC;
  __shared__ __align__(16) float BC[2][TC][256];  // 64 KB
  __shared__ __align__(16) float DT[2][TC][8];    // 2 KB
  __shared__ __align__(16) float US[2][TC][8];    // 2 KB
  __shared__ __align__(16) float ZS[2][TC][8];    // 2 KB

  int blk = blockIdx.x;
  int b = blk >> 8;
  int d0 = (blk & 255) * 8;
  int tid = threadIdx.x;
  int wave = tid >> 6, lane = tid & 63;
  int c = tid >> 5, g = tid & 31;  // channel-in-block, state group
  int d = d0 + c;

  float a0 = -__expf(A_log[d * 128 + 4 * g + 0]);
  float a1 = -__expf(A_log[d * 128 + 4 * g + 1]);
  float a2 = -__expf(A_log[d * 128 + 4 * g + 2]);
  float a3 = -__expf(A_log[d * 128 + 4 * g + 3]);
  float Dd = Dp[d];
  float h0 = 0.f, h1 = 0.f, h2 = 0.f, h3 = 0.f;

  size_t row0 = (size_t)b * L;
  // staging lane geometry (per wave: rows wave*8 .. wave*8+7 of the chunk)
  int srT = lane >> 3, srC = lane & 7;  // duz: lane -> (row-in-8, channel)

  // stage chunk starting at t0 into buffer s
#define STAGE(t0, s)                                                          \
  {                                                                           \
    size_t rr = row0 + (t0) + wave * 8;                                       \
    const float* srcBC = xdbl + rr * XD + 64 + lane * 4;                      \
    _Pragma("unroll") for (int r = 0; r < 8; ++r) {                           \
      gload16(srcBC, &BC[s][wave * 8 + r][0]);                                \
      srcBC += XD;                                                            \
    }                                                                         \
    size_t rz = rr + srT;                                                     \
    gload4(dtp + rz * DI + d0 + srC, &DT[s][wave * 8][0]);                    \
    gload4(xs + rz * DI + d0 + srC, &US[s][wave * 8][0]);                     \
    gload4(xz + rz * 4096 + 2048 + d0 + srC, &ZS[s][wave * 8][0]);            \
  }

  STAGE(0, 0);
  __syncthreads();  // drain vmcnt: chunk 0 visible

  unsigned short* pY = yb + row0 * DI + d;
  int buf = 0;
  for (int k = 0; k < NCHUNK; ++k) {
    int t0 = k * TC;
    if (k + 1 < NCHUNK) STAGE(t0 + TC, buf ^ 1);

#pragma unroll 4
    for (int t = 0; t < TC; ++t) {
      float4 Bv = *(const float4*)&BC[buf][t][g * 4];
      float4 Cv = *(const float4*)&BC[buf][t][128 + g * 4];
      float dtv = DT[buf][t][c];
      float uv = US[buf][t][c];
      float du = dtv * uv;
      h0 = fmaf(__expf(dtv * a0), h0, du * Bv.x);
      h1 = fmaf(__expf(dtv * a1), h1, du * Bv.y);
      h2 = fmaf(__expf(dtv * a2), h2, du * Bv.z);
      h3 = fmaf(__expf(dtv * a3), h3, du * Bv.w);
      float p = fmaf(h0, Cv.x, fmaf(h1, Cv.y, fmaf(h2, Cv.z, h3 * Cv.w)));
      p += __shfl_xor(p, 16);
      p += __shfl_xor(p, 8);
      p += __shfl_xor(p, 4);
      p += __shfl_xor(p, 2);
      p += __shfl_xor(p, 1);
      if (g == 0) {
        float zv = ZS[buf][t][c];
        float yv = fmaf(uv, Dd, p);
        yv *= zv / (1.f + __expf(-zv));  // * silu(z)
        pY[(size_t)(t0 + t) * DI] = f2b(yv);
      }
    }
    __syncthreads();  // compute reads done + next chunk's staging drained
    buf ^= 1;
  }
#undef STAGE
}

// ---------------------------------------------------------------------------
extern "C" void kernel_launch(void* const* d_in, const int* in_sizes, int n_in,
                              void* d_out, int out_size, void* d_ws, size_t ws_size,
                              hipStream_t stream) {
  const float* hidden  = (const float*)d_in[0];  // (2,2048,1024)
  const float* W_in    = (const float*)d_in[1];  // (1024,4096)
  const float* conv_w  = (const float*)d_in[2];  // (2048,1,4)
  const float* conv_b  = (const float*)d_in[3];  // (2048,)
  const float* W_xproj = (const float*)d_in[4];  // (2048,320)
  const float* W_dt    = (const float*)d_in[5];  // (64,2048)
  const float* b_dt    = (const float*)d_in[6];  // (2048,)
  const float* A_log   = (const float*)d_in[7];  // (2048,128)
  const float* Dvec    = (const float*)d_in[8];  // (2048,)
  const float* W_out   = (const float*)d_in[9];  // (2048,1024)
  float* out = (float*)d_out;                    // (2,2048,1024) fp32

  char* ws = (char*)d_ws;
  unsigned short* hb16  = (unsigned short*)(ws + 0);          //  8 MB (4096x1024 bf16)
  unsigned short* Wint  = (unsigned short*)(ws + 8388608);    //  8 MB [4096][1024]
  float*          xz    = (float*)(ws + 16777216);            // 64 MB [4096][4096]
  float*          xs    = (float*)(ws + 83886080);            // 32 MB [4096][2048]
  unsigned short* xsb   = (unsigned short*)(ws + 117440512);  // 16 MB
  float*          xdbl  = (float*)(ws + 134217728);           //  5 MB [4096][320]
  unsigned short* dtin  = (unsigned short*)(ws + 139460608);  // .5 MB [4096][64]
  unsigned short* Wxpt  = (unsigned short*)(ws + 139984896);  // 1.3MB [320][2048]
  unsigned short* Wdtt  = (unsigned short*)(ws + 141295616);  // .25MB [2048][64]
  float*          dtf   = (float*)(ws + 141557760);           // 32 MB [4096][2048]
  unsigned short* yb    = (unsigned short*)(ws + 175112192);  // 16 MB [4096][2048]
  unsigned short* Woutt = (unsigned short*)(ws + 191889408);  //  4 MB [1024][2048]

  // 1) operand conversion
  cast_b16<<<16384, 256, 0, stream>>>(hidden, hb16, 4194304);
  transpose_cast<<<dim3(128, 32), 256, 0, stream>>>(W_in, Wint, 1024, 4096);
  // 2) in_proj: xz = hidden @ W_in   (M=4096, N=4096, K=1024)
  gemm_bt<0><<<dim3(32, 32), 256, 0, stream>>>(hb16, Wint, xz, 4096, 4096, 1024, nullptr);
  // 3) causal depthwise conv + SiLU
  conv_silu_kernel<<<32768, 256, 0, stream>>>(xz, conv_w, conv_b, xs, xsb);
  // 4) x_proj: x_dbl = x @ W_xproj  (M=4096, N=320, K=2048)
  transpose_cast<<<dim3(10, 64), 256, 0, stream>>>(W_xproj, Wxpt, 2048, 320);
  gemm_bt<0><<<dim3(3, 32), 256, 0, stream>>>(xsb, Wxpt, xdbl, 4096, 320, 2048, nullptr);
  // 5) dt: softplus(dt_in @ W_dt + b_dt)  (M=4096, N=2048, K=64)
  slice_cast<<<1024, 256, 0, stream>>>(xdbl, dtin);
  transpose_cast<<<dim3(64, 2), 256, 0, stream>>>(W_dt, Wdtt, 64, 2048);
  gemm_bt<1><<<dim3(16, 32), 256, 0, stream>>>(dtin, Wdtt, dtf, 4096, 2048, 64, b_dt);
  // 6) selective scan + skip + gate -> y (bf16)
  scan_kernel<<<512, 256, 0, stream>>>(dtf, xs, xdbl, xz, A_log, Dvec, yb);
  // 7) out_proj: out = y @ W_out  (M=4096, N=1024, K=2048)
  transpose_cast<<<dim3(32, 64), 256, 0, stream>>>(W_out, Woutt, 2048, 1024);
  gemm_bt<0><<<dim3(8, 32), 256, 0, stream>>>(yb, Woutt, out, 4096, 1024, 2048, nullptr);
}

// Round 10
// 610.020 us; speedup vs baseline: 3.3180x; 1.7505x over previous
//
#include <hip/hip_runtime.h>

// ---------------------------------------------------------------------------
// Mamba block forward on MI355X (gfx950).
// B=2, L=2048, D_MODEL=1024, D_INNER=2048, D_STATE=128, D_CONV=4, DT_RANK=64
// ---------------------------------------------------------------------------

typedef short bf16x8 __attribute__((ext_vector_type(8)));
typedef float f32x4 __attribute__((ext_vector_type(4)));

typedef __attribute__((address_space(1))) const unsigned int GASU;
typedef __attribute__((address_space(3))) unsigned int LASU;

__device__ __forceinline__ void gload16(const void* g, void* l) {
  __builtin_amdgcn_global_load_lds((GASU*)g, (LASU*)l, 16, 0, 0);
}
__device__ __forceinline__ void gload4(const void* g, void* l) {
  __builtin_amdgcn_global_load_lds((GASU*)g, (LASU*)l, 4, 0, 0);
}

// round-to-nearest-even f32 -> bf16 bits
__device__ __forceinline__ unsigned short f2b(float f) {
  unsigned int u = __float_as_uint(f);
  unsigned int r = u + 0x7FFFu + ((u >> 16) & 1u);
  return (unsigned short)(r >> 16);
}

// ---------------------------------------------------------------------------
// elementwise cast fp32 -> bf16
__global__ __launch_bounds__(256) void cast_b16(const float* __restrict__ in,
                                                unsigned short* __restrict__ out,
                                                int n) {
  int i = blockIdx.x * 256 + threadIdx.x;
  if (i < n) out[i] = f2b(in[i]);
}

// ---------------------------------------------------------------------------
// transpose + cast: out[c][r] = bf16(in[r][c]).  R, C multiples of 32.
__global__ __launch_bounds__(256) void transpose_cast(const float* __restrict__ in,
                                                      unsigned short* __restrict__ out,
                                                      int R, int C) {
  __shared__ float tile[32][33];
  int bx = blockIdx.x * 32;  // col base (in)
  int by = blockIdx.y * 32;  // row base (in)
  int lx = threadIdx.x & 31, ly = threadIdx.x >> 5;  // ly: 0..7
#pragma unroll
  for (int i = 0; i < 32; i += 8)
    tile[ly + i][lx] = in[(size_t)(by + ly + i) * C + bx + lx];
  __syncthreads();
#pragma unroll
  for (int i = 0; i < 32; i += 8)
    out[(size_t)(bx + ly + i) * R + by + lx] = f2b(tile[lx][ly + i]);
}

// ---------------------------------------------------------------------------
// bf16 MFMA GEMM: C[M][N] (fp32) = A[M][K] (bf16) * Bt[N][K]^T (bf16)
// 128x128 tile, BK=32, 256 threads (4 waves, each a 64x64 quadrant of 4x4
// 16x16x32 MFMAs). global_load_lds width-16 staging (m97 structure).
// EPI==1: C = softplus(C + bias[col])
// M multiple of 128, K multiple of 32. N arbitrary (edge-masked store).
template <int EPI>
__global__ __launch_bounds__(256) void gemm_bt(const unsigned short* __restrict__ A,
                                               const unsigned short* __restrict__ Bt,
                                               float* __restrict__ C, int M, int N,
                                               int K, const float* __restrict__ bias) {
  __shared__ __align__(16) unsigned short As[128 * 32];
  __shared__ __align__(16) unsigned short Bs[128 * 32];
  int tid = threadIdx.x;
  int wave = tid >> 6, lane = tid & 63;
  int m0 = blockIdx.y * 128, n0 = blockIdx.x * 128;
  int wm = (wave >> 1) * 64, wn = (wave & 1) * 64;

  f32x4 acc[4][4];
#pragma unroll
  for (int i = 0; i < 4; i++)
#pragma unroll
    for (int j = 0; j < 4; j++) acc[i][j] = (f32x4){0.f, 0.f, 0.f, 0.f};

  // staging geometry: each issue covers 64 rows x 32 cols (bf16); a wave
  // covers 16 rows (1 KiB). lane -> row = base + lane/4, col8 = (lane%4)*8.
  int srow = wave * 16 + (lane >> 2);
  int scol = (lane & 3) * 8;
  unsigned short* lA0 = &As[(wave * 16) * 32];
  unsigned short* lA1 = &As[(64 + wave * 16) * 32];
  unsigned short* lB0 = &Bs[(wave * 16) * 32];
  unsigned short* lB1 = &Bs[(64 + wave * 16) * 32];

  for (int k0 = 0; k0 < K; k0 += 32) {
    const unsigned short* gA0 = A + (size_t)(m0 + srow) * K + k0 + scol;
    const unsigned short* gA1 = A + (size_t)(m0 + 64 + srow) * K + k0 + scol;
    int rb0 = n0 + srow;      if (rb0 > N - 1) rb0 = N - 1;
    int rb1 = n0 + 64 + srow; if (rb1 > N - 1) rb1 = N - 1;
    const unsigned short* gB0 = Bt + (size_t)rb0 * K + k0 + scol;
    const unsigned short* gB1 = Bt + (size_t)rb1 * K + k0 + scol;
    gload16(gA0, lA0);
    gload16(gA1, lA1);
    gload16(gB0, lB0);
    gload16(gB1, lB1);
    __syncthreads();  // drains vmcnt: staged tile visible to all waves

    int lm = lane & 15, kk = (lane >> 4) * 8;
    bf16x8 af[4], bfr[4];
#pragma unroll
    for (int i = 0; i < 4; i++)
      af[i] = *(const bf16x8*)&As[(wm + i * 16 + lm) * 32 + kk];
#pragma unroll
    for (int j = 0; j < 4; j++)
      bfr[j] = *(const bf16x8*)&Bs[(wn + j * 16 + lm) * 32 + kk];
#pragma unroll
    for (int i = 0; i < 4; i++)
#pragma unroll
      for (int j = 0; j < 4; j++)
        acc[i][j] = __builtin_amdgcn_mfma_f32_16x16x32_bf16(af[i], bfr[j],
                                                            acc[i][j], 0, 0, 0);
    __syncthreads();  // all reads done before next-tile overwrite
  }

  // C/D layout (verified): col = lane&15, row = (lane>>4)*4 + reg
  int lm = lane & 15;
  int r0 = m0 + wm + (lane >> 4) * 4;
#pragma unroll
  for (int i = 0; i < 4; i++) {
#pragma unroll
    for (int j = 0; j < 4; j++) {
      int col = n0 + wn + j * 16 + lm;
      if (col < N) {
#pragma unroll
        for (int q = 0; q < 4; q++) {
          float v = acc[i][j][q];
          if (EPI == 1) {
            v += bias[col];
            v = (v > 20.f) ? v : __logf(1.f + __expf(v));
          }
          C[(size_t)(r0 + i * 16 + q) * N + col] = v;
        }
      }
    }
  }
}

// ---------------------------------------------------------------------------
// causal depthwise conv (k=4) + bias + SiLU.  x = xz[:, 0:2048].
// writes x_silu fp32 (scan input u) and bf16 (x_proj GEMM input).
__global__ __launch_bounds__(256) void conv_silu_kernel(
    const float* __restrict__ xz, const float* __restrict__ cw,
    const float* __restrict__ cb, float* __restrict__ xs,
    unsigned short* __restrict__ xsb) {
  int idx = blockIdx.x * 256 + threadIdx.x;  // over 4096*2048
  int d = idx & 2047;
  int row = idx >> 11;  // b*2048 + t
  int t = row & 2047;
  float w0 = cw[d * 4 + 0], w1 = cw[d * 4 + 1], w2 = cw[d * 4 + 2],
        w3 = cw[d * 4 + 3];
  float acc = cb[d];
  if (t >= 3) acc = fmaf(w0, xz[(size_t)(row - 3) * 4096 + d], acc);
  if (t >= 2) acc = fmaf(w1, xz[(size_t)(row - 2) * 4096 + d], acc);
  if (t >= 1) acc = fmaf(w2, xz[(size_t)(row - 1) * 4096 + d], acc);
  acc = fmaf(w3, xz[(size_t)row * 4096 + d], acc);
  float s = acc / (1.f + __expf(-acc));
  xs[(size_t)row * 2048 + d] = s;
  xsb[(size_t)row * 2048 + d] = f2b(s);
}

// ---------------------------------------------------------------------------
// slice x_dbl[:, 0:64] -> bf16 (dt GEMM A operand)
__global__ __launch_bounds__(256) void slice_cast(const float* __restrict__ xdbl,
                                                  unsigned short* __restrict__ dtin) {
  int idx = blockIdx.x * 256 + threadIdx.x;  // 4096*64
  int r = idx >> 6, i = idx & 63;
  dtin[idx] = f2b(xdbl[(size_t)r * 320 + i]);
}

// ---------------------------------------------------------------------------
// selective scan v4: time-tiled LDS staging + DEFERRED cross-lane reduction.
// Block = 256 threads = 8 channels x (32 lanes x 4 states); grid = 512.
// v3's per-t 5-shfl serial reduction (latency-bound at 2 waves/SIMD) is
// replaced by: inner loop writes per-lane partials to P (1 ds_write, no
// cross-lane deps); once per TC=16 chunk the wave does a transposed reduce
// (lane l sums the 32 partials of t=l&15), applies skip+gate, stores y.
// P is wave-local: ordered by lgkmcnt(0)+sched_barrier (rule #18), no extra
// block barrier. Staging (all 5 streams) via global_load_lds as in v3.
__global__ __launch_bounds__(256) void scan_kernel(
    const float* __restrict__ dtp, const float* __restrict__ xs,
    const float* __restrict__ xdbl, const float* __restrict__ xz,
    const float* __restrict__ A_log, const float* __restrict__ Dp,
    unsigned short* __restrict__ yb) {
  const int L = 2048, DI = 2048, XD = 320, TC = 16;
  const int NCHUNK = L / TC;  // 128
  __shared__ __align__(16) float BC[2][TC][256];  // 32 KB  B|C (cols 64..320)
  __shared__ __align__(16) float DU[2][TC][16];   //  2 KB  [t][0..7]=dt [8..15]=u
  __shared__ __align__(16) float ZS[2][TC][8];    //  1 KB  z
  __shared__ __align__(16) float P[8][TC][36];    // 18.4KB partials (36: 16B-align + bank spread)

  int blk = blockIdx.x;
  int b = blk >> 8;
  int d0 = (blk & 255) * 8;
  int tid = threadIdx.x;
  int wave = tid >> 6, lane = tid & 63;
  int c = tid >> 5, g = tid & 31;  // channel-in-block, state group
  int d = d0 + c;

  float a0 = -__expf(A_log[d * 128 + 4 * g + 0]);
  float a1 = -__expf(A_log[d * 128 + 4 * g + 1]);
  float a2 = -__expf(A_log[d * 128 + 4 * g + 2]);
  float a3 = -__expf(A_log[d * 128 + 4 * g + 3]);
  float Dd = Dp[d];
  float h0 = 0.f, h1 = 0.f, h2 = 0.f, h3 = 0.f;

  size_t row0 = (size_t)b * L;
  int rt = lane & 15;          // reduce-phase: my t within chunk
  int half = (lane >> 4) & 1;  // reduce-phase: my 16-partial half

  // stage chunk starting at t0 into buffer s.
  // BC: wave stages rows 4w..4w+3 (1 gload16 each; lane l covers floats 4l..4l+3).
  // DU: 1 gload4/wave covers rows 4w..4w+3 x 16 (dt|u per-lane source select).
  // ZS: waves 0-1 only, rows 8w..8w+7 x 8.
#define STAGE(t0, s)                                                          \
  {                                                                           \
    size_t rbase = row0 + (t0);                                               \
    const float* srcBC = xdbl + (rbase + wave * 4) * XD + 64 + lane * 4;      \
    _Pragma("unroll") for (int r = 0; r < 4; ++r) {                           \
      gload16(srcBC, &BC[s][wave * 4 + r][0]);                                \
      srcBC += XD;                                                            \
    }                                                                         \
    {                                                                         \
      int trow = wave * 4 + (lane >> 4), slot = lane & 15;                    \
      const float* sdu = (slot < 8)                                           \
                             ? (dtp + (rbase + trow) * DI + d0 + slot)        \
                             : (xs + (rbase + trow) * DI + d0 + (slot - 8));  \
      gload4(sdu, &DU[s][wave * 4][0]);                                       \
    }                                                                         \
    if (wave < 2) {                                                           \
      int trow = wave * 8 + (lane >> 3);                                      \
      gload4(xz + (rbase + trow) * 4096 + 2048 + d0 + (lane & 7),             \
             &ZS[s][wave * 8][0]);                                            \
    }                                                                         \
  }

  STAGE(0, 0);
  __syncthreads();  // drain vmcnt: chunk 0 visible

  int buf = 0;
  for (int k = 0; k < NCHUNK; ++k) {
    int t0 = k * TC;
    if (k + 1 < NCHUNK) STAGE(t0 + TC, buf ^ 1);

    // compute phase: no cross-lane ops, no branches; h-chain is the only
    // serial dependence (one fma latency per t).
#pragma unroll
    for (int t = 0; t < TC; ++t) {
      float4 Bv = *(const float4*)&BC[buf][t][4 * g];
      float4 Cv = *(const float4*)&BC[buf][t][128 + 4 * g];
      float dtv = DU[buf][t][c];
      float uv = DU[buf][t][8 + c];
      float du = dtv * uv;
      h0 = fmaf(__expf(dtv * a0), h0, du * Bv.x);
      h1 = fmaf(__expf(dtv * a1), h1, du * Bv.y);
      h2 = fmaf(__expf(dtv * a2), h2, du * Bv.z);
      h3 = fmaf(__expf(dtv * a3), h3, du * Bv.w);
      P[c][t][g] = fmaf(h0, Cv.x, fmaf(h1, Cv.y, fmaf(h2, Cv.z, h3 * Cv.w)));
    }

    // wave-local ordering: P writes visible to this wave's reads (rule #18:
    // explicit lgkmcnt + sched_barrier so reads aren't hoisted above it).
    asm volatile("s_waitcnt lgkmcnt(0)" ::: "memory");
    __builtin_amdgcn_sched_barrier(0);

    // reduce phase: lane sums 16 partials of t=rt, combine halves via 1 shfl.
    {
      const float* pr = &P[c][rt][16 * half];
      float4 q0 = *(const float4*)(pr);
      float4 q1 = *(const float4*)(pr + 4);
      float4 q2 = *(const float4*)(pr + 8);
      float4 q3 = *(const float4*)(pr + 12);
      float s01 = ((q0.x + q0.y) + (q0.z + q0.w)) +
                  ((q1.x + q1.y) + (q1.z + q1.w));
      float s23 = ((q2.x + q2.y) + (q2.z + q2.w)) +
                  ((q3.x + q3.y) + (q3.z + q3.w));
      float s = s01 + s23;
      s += __shfl_xor(s, 16);
      if (half == 0) {
        float uvr = DU[buf][rt][8 + c];
        float zr = ZS[buf][rt][c];
        float yv = fmaf(uvr, Dd, s);
        yv *= zr / (1.f + __expf(-zr));  // * silu(z)
        yb[(row0 + t0 + rt) * DI + d] = f2b(yv);
      }
    }
    __syncthreads();  // staging k+1 drained + all buf reads done
    buf ^= 1;
  }
#undef STAGE
}

// ---------------------------------------------------------------------------
extern "C" void kernel_launch(void* const* d_in, const int* in_sizes, int n_in,
                              void* d_out, int out_size, void* d_ws, size_t ws_size,
                              hipStream_t stream) {
  const float* hidden  = (const float*)d_in[0];  // (2,2048,1024)
  const float* W_in    = (const float*)d_in[1];  // (1024,4096)
  const float* conv_w  = (const float*)d_in[2];  // (2048,1,4)
  const float* conv_b  = (const float*)d_in[3];  // (2048,)
  const float* W_xproj = (const float*)d_in[4];  // (2048,320)
  const float* W_dt    = (const float*)d_in[5];  // (64,2048)
  const float* b_dt    = (const float*)d_in[6];  // (2048,)
  const float* A_log   = (const float*)d_in[7];  // (2048,128)
  const float* Dvec    = (const float*)d_in[8];  // (2048,)
  const float* W_out   = (const float*)d_in[9];  // (2048,1024)
  float* out = (float*)d_out;                    // (2,2048,1024) fp32

  char* ws = (char*)d_ws;
  unsigned short* hb16  = (unsigned short*)(ws + 0);          //  8 MB (4096x1024 bf16)
  unsigned short* Wint  = (unsigned short*)(ws + 8388608);    //  8 MB [4096][1024]
  float*          xz    = (float*)(ws + 16777216);            // 64 MB [4096][4096]
  float*          xs    = (float*)(ws + 83886080);            // 32 MB [4096][2048]
  unsigned short* xsb   = (unsigned short*)(ws + 117440512);  // 16 MB
  float*          xdbl  = (float*)(ws + 134217728);           //  5 MB [4096][320]
  unsigned short* dtin  = (unsigned short*)(ws + 139460608);  // .5 MB [4096][64]
  unsigned short* Wxpt  = (unsigned short*)(ws + 139984896);  // 1.3MB [320][2048]
  unsigned short* Wdtt  = (unsigned short*)(ws + 141295616);  // .25MB [2048][64]
  float*          dtf   = (float*)(ws + 141557760);           // 32 MB [4096][2048]
  unsigned short* yb    = (unsigned short*)(ws + 175112192);  // 16 MB [4096][2048]
  unsigned short* Woutt = (unsigned short*)(ws + 191889408);  //  4 MB [1024][2048]

  // 1) operand conversion
  cast_b16<<<16384, 256, 0, stream>>>(hidden, hb16, 4194304);
  transpose_cast<<<dim3(128, 32), 256, 0, stream>>>(W_in, Wint, 1024, 4096);
  // 2) in_proj: xz = hidden @ W_in   (M=4096, N=4096, K=1024)
  gemm_bt<0><<<dim3(32, 32), 256, 0, stream>>>(hb16, Wint, xz, 4096, 4096, 1024, nullptr);
  // 3) causal depthwise conv + SiLU
  conv_silu_kernel<<<32768, 256, 0, stream>>>(xz, conv_w, conv_b, xs, xsb);
  // 4) x_proj: x_dbl = x @ W_xproj  (M=4096, N=320, K=2048)
  transpose_cast<<<dim3(10, 64), 256, 0, stream>>>(W_xproj, Wxpt, 2048, 320);
  gemm_bt<0><<<dim3(3, 32), 256, 0, stream>>>(xsb, Wxpt, xdbl, 4096, 320, 2048, nullptr);
  // 5) dt: softplus(dt_in @ W_dt + b_dt)  (M=4096, N=2048, K=64)
  slice_cast<<<1024, 256, 0, stream>>>(xdbl, dtin);
  transpose_cast<<<dim3(64, 2), 256, 0, stream>>>(W_dt, Wdtt, 64, 2048);
  gemm_bt<1><<<dim3(16, 32), 256, 0, stream>>>(dtin, Wdtt, dtf, 4096, 2048, 64, b_dt);
  // 6) selective scan + skip + gate -> y (bf16)
  scan_kernel<<<512, 256, 0, stream>>>(dtf, xs, xdbl, xz, A_log, Dvec, yb);
  // 7) out_proj: out = y @ W_out  (M=4096, N=1024, K=2048)
  transpose_cast<<<dim3(32, 64), 256, 0, stream>>>(W_out, Woutt, 2048, 1024);
  gemm_bt<0><<<dim3(8, 32), 256, 0, stream>>>(yb, Woutt, out, 4096, 1024, 2048, nullptr);
}